// Round 1
// baseline (582.080 us; speedup 1.0000x reference)
//
#include <hip/hip_runtime.h>
#include <hip/hip_bf16.h>
#include <math.h>

#define C_CLS   1024
#define NPROXY  8
#define ALLNUM  8192
#define DIM     512
#define TOPK    410
#define LAM     0.3f
#define BATCH   2048

// ws layout (floats):
//   rnorm [ALLNUM] | S [DIM*C_CLS] | sim [BATCH*ALLNUM] | accs[2]
#define WS_RNORM 0
#define WS_S     (ALLNUM)
#define WS_SIM   (WS_S + DIM * C_CLS)
#define WS_ACC   (WS_SIM + (size_t)BATCH * ALLNUM)

// ---------------- block reduction helper (256 threads = 4 waves) -------------
__device__ inline float block_reduce(float v, int is_max, float* red, int t) {
    #pragma unroll
    for (int o = 32; o > 0; o >>= 1) {
        float w = __shfl_down(v, o);
        v = is_max ? fmaxf(v, w) : (v + w);
    }
    __syncthreads();                 // protect red[] from previous use
    if ((t & 63) == 0) red[t >> 6] = v;
    __syncthreads();
    return is_max ? fmaxf(fmaxf(red[0], red[1]), fmaxf(red[2], red[3]))
                  : (red[0] + red[1] + red[2] + red[3]);
}

// ---------------- K1: column 1/norms + zero accumulators ---------------------
__global__ __launch_bounds__(256) void k_colnorm(const float* __restrict__ P,
                                                 float* __restrict__ rnorm,
                                                 float* __restrict__ accs) {
    int j = blockIdx.x * 256 + threadIdx.x;
    float s = 0.f;
    #pragma unroll 8
    for (int d = 0; d < DIM; ++d) {
        float v = P[(size_t)d * ALLNUM + j];
        s += v * v;
    }
    rnorm[j] = 1.0f / fmaxf(sqrtf(s), 1e-12f);
    if (j < 2) accs[j] = 0.f;
}

// ---------------- K2: S[d][c] = sum_{n<8} P[d][8c+n] * rnorm[8c+n] -----------
__global__ __launch_bounds__(256) void k_buildS(const float* __restrict__ P,
                                                const float* __restrict__ rnorm,
                                                float* __restrict__ S) {
    int idx = blockIdx.x * 256 + threadIdx.x;    // 0 .. DIM*C_CLS-1
    int d = idx >> 10;
    int c = idx & (C_CLS - 1);
    const float* p = P + (size_t)d * ALLNUM + c * NPROXY;
    const float* rn = rnorm + c * NPROXY;
    float4 a = *(const float4*)p;
    float4 b = *(const float4*)(p + 4);
    float4 ra = *(const float4*)rn;
    float4 rb = *(const float4*)(rn + 4);
    S[idx] = a.x * ra.x + a.y * ra.y + a.z * ra.z + a.w * ra.w +
             b.x * rb.x + b.y * rb.y + b.z * rb.z + b.w * rb.w;
}

// ---------------- K3: sim = input @ P, scaled by rnorm (64x64 tiles) ---------
__global__ __launch_bounds__(256) void k_sim(const float* __restrict__ A,
                                             const float* __restrict__ Bm,
                                             const float* __restrict__ rnorm,
                                             float* __restrict__ sim) {
    __shared__ float As[16][64];
    __shared__ float Bs[16][64];
    int t  = threadIdx.x;
    int bj = blockIdx.x * 64;
    int bi = blockIdx.y * 64;
    int tx = t & 15, ty = t >> 4;
    float acc[4][4];
    #pragma unroll
    for (int r = 0; r < 4; ++r)
        #pragma unroll
        for (int c = 0; c < 4; ++c) acc[r][c] = 0.f;

    for (int k0 = 0; k0 < DIM; k0 += 16) {
        #pragma unroll
        for (int p = 0; p < 4; ++p) {
            int l = t + 256 * p;           // 0..1023 = 64 rows x 16 k
            int r = l >> 4, kk = l & 15;
            As[kk][r] = A[(size_t)(bi + r) * DIM + k0 + kk];
        }
        #pragma unroll
        for (int p = 0; p < 4; ++p) {
            int l = t + 256 * p;           // 0..1023 = 16 k x 64 cols
            int kk = l >> 6, c = l & 63;
            Bs[kk][c] = Bm[(size_t)(k0 + kk) * ALLNUM + bj + c];
        }
        __syncthreads();
        #pragma unroll
        for (int kk = 0; kk < 16; ++kk) {
            float4 a4 = *(const float4*)&As[kk][ty * 4];
            float4 b4 = *(const float4*)&Bs[kk][tx * 4];
            acc[0][0] += a4.x * b4.x; acc[0][1] += a4.x * b4.y;
            acc[0][2] += a4.x * b4.z; acc[0][3] += a4.x * b4.w;
            acc[1][0] += a4.y * b4.x; acc[1][1] += a4.y * b4.y;
            acc[1][2] += a4.y * b4.z; acc[1][3] += a4.y * b4.w;
            acc[2][0] += a4.z * b4.x; acc[2][1] += a4.z * b4.y;
            acc[2][2] += a4.z * b4.z; acc[2][3] += a4.z * b4.w;
            acc[3][0] += a4.w * b4.x; acc[3][1] += a4.w * b4.y;
            acc[3][2] += a4.w * b4.z; acc[3][3] += a4.w * b4.w;
        }
        __syncthreads();
    }
    float4 rn = *(const float4*)&rnorm[bj + tx * 4];
    #pragma unroll
    for (int r = 0; r < 4; ++r) {
        int gr = bi + ty * 4 + r;
        float4 o;
        o.x = acc[r][0] * rn.x; o.y = acc[r][1] * rn.y;
        o.z = acc[r][2] * rn.z; o.w = acc[r][3] * rn.w;
        *(float4*)&sim[(size_t)gr * ALLNUM + bj + tx * 4] = o;
    }
}

// ---------------- K4: per-row topk select + class sums + loss ----------------
__device__ inline unsigned f2ord(float f) {
    unsigned u = __float_as_uint(f);
    return (u & 0x80000000u) ? ~u : (u | 0x80000000u);
}

__global__ __launch_bounds__(256) void k_rowloss(const float* __restrict__ sim,
                                                 const int* __restrict__ target,
                                                 float* __restrict__ accs) {
    __shared__ float    s_val[ALLNUM];        // 32 KB row cache
    __shared__ float    s_cls[C_CLS];         // 4 KB class bins
    __shared__ unsigned s_hist[4][256];       // per-wave histograms
    __shared__ unsigned s_scan[256];
    __shared__ unsigned sh_pref;
    __shared__ int      sh_k;
    __shared__ float    red[4];

    int b = blockIdx.x, t = threadIdx.x;
    const float* row = sim + (size_t)b * ALLNUM;
    int tgt = target[b];
    int jt0 = tgt * NPROXY;

    for (int i = t; i < ALLNUM; i += 256) s_val[i] = row[i];
    for (int i = t; i < C_CLS; i += 256) s_cls[i] = 0.f;
    if (t == 0) { sh_pref = 0u; sh_k = TOPK; }
    __syncthreads();

    unsigned pmask = 0u;
    int wid = t >> 6;
    for (int shift = 24; shift >= 0; shift -= 8) {
        s_hist[0][t] = 0; s_hist[1][t] = 0; s_hist[2][t] = 0; s_hist[3][t] = 0;
        __syncthreads();
        unsigned prefc = sh_pref;
        int kcur = sh_k;
        for (int i = t; i < ALLNUM; i += 256) {
            float f = s_val[i] + (((unsigned)(i - jt0) < (unsigned)NPROXY) ? 1000.0f : 0.0f);
            unsigned u = f2ord(f);
            if ((u & pmask) == prefc)
                atomicAdd(&s_hist[wid][(u >> shift) & 255], 1u);
        }
        __syncthreads();
        unsigned h = s_hist[0][t] + s_hist[1][t] + s_hist[2][t] + s_hist[3][t];
        s_scan[t] = h;
        __syncthreads();
        // inclusive suffix sum: s_scan[t] = count of values with digit >= t
        for (int off = 1; off < 256; off <<= 1) {
            unsigned v = (t + off < 256) ? s_scan[t + off] : 0u;
            __syncthreads();
            s_scan[t] += v;
            __syncthreads();
        }
        unsigned cumGE = s_scan[t];
        if (cumGE >= (unsigned)kcur && cumGE - h < (unsigned)kcur) {
            sh_pref = prefc | ((unsigned)t << shift);
            sh_k = kcur - (int)(cumGE - h);
        }
        pmask |= (0xFFu << shift);
        __syncthreads();
    }
    unsigned thr = sh_pref;   // bit pattern of the TOPK-th largest boosted value

    for (int i = t; i < ALLNUM; i += 256) {
        float f = s_val[i] + (((unsigned)(i - jt0) < (unsigned)NPROXY) ? 1000.0f : 0.0f);
        if (f2ord(f) >= thr)
            atomicAdd(&s_cls[i >> 3], s_val[i]);   // original sim, per prob_a
    }
    __syncthreads();

    // masked (logit != 0) stable softmax loss
    float m = -1e30f;
    for (int c = t; c < C_CLS; c += 256) {
        float v = s_cls[c];
        if (v != 0.0f) m = fmaxf(m, v);
    }
    m = block_reduce(m, 1, red, t);
    float se = 0.f;
    for (int c = t; c < C_CLS; c += 256) {
        float v = s_cls[c];
        if (v != 0.0f) se += expf(v - m);
    }
    se = block_reduce(se, 0, red, t);
    if (t == 0) {
        float lt = s_cls[tgt];
        float predict_t = expf(lt - m) / (1e-8f * expf(-m) + se);
        float loss = -logf(predict_t + 1e-20f);
        atomicAdd(&accs[0], loss);
    }
}

// ---------------- K5: reg GEMM (P^T @ S) + fused log_softmax diag ------------
__global__ __launch_bounds__(256) void k_reg(const float* __restrict__ P,
                                             const float* __restrict__ S,
                                             const float* __restrict__ rnorm,
                                             float* __restrict__ accs) {
    __shared__ float As[32][16];
    __shared__ float red[4];
    __shared__ float sdiag;
    int t = threadIdx.x;
    int i0 = blockIdx.x * 16;

    float acc[16][4];
    #pragma unroll
    for (int r = 0; r < 16; ++r)
        #pragma unroll
        for (int q = 0; q < 4; ++q) acc[r][q] = 0.f;

    for (int d0 = 0; d0 < DIM; d0 += 32) {
        #pragma unroll
        for (int p = 0; p < 2; ++p) {
            int l = t + 256 * p;             // 0..511 = 32 d x 16 rows
            int dd = l >> 4, r = l & 15;
            As[dd][r] = P[(size_t)(d0 + dd) * ALLNUM + i0 + r];
        }
        __syncthreads();
        #pragma unroll
        for (int dd = 0; dd < 32; ++dd) {
            const float* srow = S + (size_t)(d0 + dd) * C_CLS;
            float sv0 = srow[t];
            float sv1 = srow[t + 256];
            float sv2 = srow[t + 512];
            float sv3 = srow[t + 768];
            #pragma unroll
            for (int r = 0; r < 16; ++r) {
                float a = As[dd][r];
                acc[r][0] += a * sv0;
                acc[r][1] += a * sv1;
                acc[r][2] += a * sv2;
                acc[r][3] += a * sv3;
            }
        }
        __syncthreads();
    }

    float regsum = 0.f;
    for (int r = 0; r < 16; ++r) {
        int i = i0 + r;
        float rn = rnorm[i];
        float v0 = acc[r][0] * rn, v1 = acc[r][1] * rn;
        float v2 = acc[r][2] * rn, v3 = acc[r][3] * rn;
        float mx = fmaxf(fmaxf(v0, v1), fmaxf(v2, v3));
        mx = block_reduce(mx, 1, red, t);
        float se = expf(v0 - mx) + expf(v1 - mx) + expf(v2 - mx) + expf(v3 - mx);
        se = block_reduce(se, 0, red, t);
        int ci = i >> 3;                      // diag class for row i
        if (t == (ci & 255)) {
            int q = ci >> 8;
            sdiag = (q == 0) ? v0 : (q == 1) ? v1 : (q == 2) ? v2 : v3;
        }
        __syncthreads();
        if (t == 0) regsum += mx + logf(se) - sdiag;
        __syncthreads();
    }
    if (t == 0) atomicAdd(&accs[1], regsum);
}

// ---------------- K6: finalize ------------------------------------------------
__global__ void k_final(const float* __restrict__ accs, float* __restrict__ out) {
    float lc = accs[0] / (float)BATCH;
    float rg = accs[1] / (float)ALLNUM;
    out[0] = lc + LAM * rg;
    out[1] = lc;
}

extern "C" void kernel_launch(void* const* d_in, const int* in_sizes, int n_in,
                              void* d_out, int out_size, void* d_ws, size_t ws_size,
                              hipStream_t stream) {
    const float* input  = (const float*)d_in[0];
    const int*   target = (const int*)d_in[1];
    const float* P      = (const float*)d_in[2];
    // d_in[3] (instance_label) is structural: class(j) = j >> 3

    float* ws    = (float*)d_ws;
    float* rnorm = ws + WS_RNORM;
    float* S     = ws + WS_S;
    float* sim   = ws + WS_SIM;
    float* accs  = ws + WS_ACC;
    float* out   = (float*)d_out;

    hipLaunchKernelGGL(k_colnorm, dim3(ALLNUM / 256), dim3(256), 0, stream, P, rnorm, accs);
    hipLaunchKernelGGL(k_buildS, dim3(DIM * C_CLS / 256), dim3(256), 0, stream, P, rnorm, S);
    hipLaunchKernelGGL(k_sim, dim3(ALLNUM / 64, BATCH / 64), dim3(256), 0, stream,
                       input, P, rnorm, sim);
    hipLaunchKernelGGL(k_rowloss, dim3(BATCH), dim3(256), 0, stream, sim, target, accs);
    hipLaunchKernelGGL(k_reg, dim3(ALLNUM / 16), dim3(256), 0, stream, P, S, rnorm, accs);
    hipLaunchKernelGGL(k_final, dim3(1), dim3(1), 0, stream, accs, out);
}

// Round 2
// 275.918 us; speedup vs baseline: 2.1096x; 2.1096x over previous
//
#include <hip/hip_runtime.h>
#include <hip/hip_bf16.h>
#include <math.h>

#define C_CLS   1024
#define NPROXY  8
#define ALLNUM  8192
#define DIM     512
#define TOPK    410
#define LAM     0.3f
#define BATCH   2048

typedef __bf16 bf16x8 __attribute__((ext_vector_type(8)));
typedef float floatx4 __attribute__((ext_vector_type(4)));
typedef unsigned short ushort_t;

// ws layout (float offsets)
#define WS_RNORM 0                      // 8192
#define WS_S     8192                   // 512*1024 fp32 = 524288
#define WS_ABF   532480                 // 2048*512 bf16 = 524288 float-slots
#define WS_PBF   1056768                // 8192*512 bf16 = 2097152 float-slots
#define WS_STBF  3153920                // 1024*512 bf16 = 262144 float-slots
#define WS_ACC   3416064                // 2
#define WS_SIM   3416080                // 2048*8192 fp32 (logits [8192][1024] aliases this)

// ---------------- helpers ----------------------------------------------------
__device__ inline float block_reduce(float v, int is_max, float* red, int t) {
    #pragma unroll
    for (int o = 32; o > 0; o >>= 1) {
        float w = __shfl_down(v, o);
        v = is_max ? fmaxf(v, w) : (v + w);
    }
    __syncthreads();
    if ((t & 63) == 0) red[t >> 6] = v;
    __syncthreads();
    return is_max ? fmaxf(fmaxf(red[0], red[1]), fmaxf(red[2], red[3]))
                  : (red[0] + red[1] + red[2] + red[3]);
}

__device__ inline ushort_t f2bf(float f) {   // RNE float->bf16
    unsigned u = __float_as_uint(f);
    return (ushort_t)((u + 0x7FFFu + ((u >> 16) & 1u)) >> 16);
}

__device__ inline void ld_g2l_16(const void* g, void* l) {
    __builtin_amdgcn_global_load_lds(
        (const __attribute__((address_space(1))) unsigned int*)g,
        (__attribute__((address_space(3))) unsigned int*)l,
        16, 0, 0);
}

// ---------------- K1: column 1/norms + zero accumulators ---------------------
__global__ __launch_bounds__(256) void k_colnorm(const float* __restrict__ P,
                                                 float* __restrict__ rnorm,
                                                 float* __restrict__ accs) {
    int j = blockIdx.x * 256 + threadIdx.x;
    float s = 0.f;
    #pragma unroll 8
    for (int d = 0; d < DIM; ++d) {
        float v = P[(size_t)d * ALLNUM + j];
        s += v * v;
    }
    rnorm[j] = 1.0f / fmaxf(sqrtf(s), 1e-12f);
    if (j < 2) accs[j] = 0.f;
}

// ---------------- K2: S[d][c] = sum_{n<8} P[d][8c+n] * rnorm[8c+n] -----------
__global__ __launch_bounds__(256) void k_buildS(const float* __restrict__ P,
                                                const float* __restrict__ rnorm,
                                                float* __restrict__ S) {
    int idx = blockIdx.x * 256 + threadIdx.x;
    int d = idx >> 10;
    int c = idx & (C_CLS - 1);
    const float* p = P + (size_t)d * ALLNUM + c * NPROXY;
    const float* rn = rnorm + c * NPROXY;
    float4 a = *(const float4*)p;
    float4 b = *(const float4*)(p + 4);
    float4 ra = *(const float4*)rn;
    float4 rb = *(const float4*)(rn + 4);
    S[idx] = a.x * ra.x + a.y * ra.y + a.z * ra.z + a.w * ra.w +
             b.x * rb.x + b.y * rb.y + b.z * rb.z + b.w * rb.w;
}

// ---------------- conv: fp32 -> bf16, same layout ----------------------------
__global__ __launch_bounds__(256) void k_convA(const float* __restrict__ src,
                                               ushort_t* __restrict__ dst) {
    int idx = blockIdx.x * 256 + threadIdx.x;          // per float4
    float4 v = ((const float4*)src)[idx];
    ushort4 o;
    o.x = f2bf(v.x); o.y = f2bf(v.y); o.z = f2bf(v.z); o.w = f2bf(v.w);
    ((ushort4*)dst)[idx] = o;
}

// ---------------- conv: fp32 [R][Cc] -> bf16 [Cc][R] (transpose) -------------
__global__ __launch_bounds__(256) void k_tconv(const float* __restrict__ src,
                                               ushort_t* __restrict__ dst,
                                               int R, int Cc) {
    __shared__ float tile[32][33];
    int c0 = blockIdx.x * 32, r0 = blockIdx.y * 32;
    int tc = threadIdx.x & 31, tr = threadIdx.x >> 5;   // tr 0..7
    #pragma unroll
    for (int p = 0; p < 4; ++p)
        tile[tr + p * 8][tc] = src[(size_t)(r0 + tr + p * 8) * Cc + c0 + tc];
    __syncthreads();
    #pragma unroll
    for (int p = 0; p < 4; ++p) {
        int oc = tr + p * 8;
        dst[(size_t)(c0 + oc) * R + r0 + tc] = f2bf(tile[tc][oc]);
    }
}

// ---------------- MFMA GEMM: C[M][N] = A[M][512] * B[N][512]^T ---------------
// MODE 0: C *= rnorm[col] (sim) ; MODE 1: C *= rnorm[row] (reg logits)
template<int MODE>
__global__ __launch_bounds__(256) void k_gemm_bt(const ushort_t* __restrict__ A,
                                                 const ushort_t* __restrict__ B,
                                                 const float* __restrict__ rnorm,
                                                 float* __restrict__ Cmat, int Ndim) {
    __shared__ __align__(16) ushort_t sA[128 * 64];
    __shared__ __align__(16) ushort_t sB[128 * 64];
    int t = threadIdx.x;
    int w = t >> 6, lane = t & 63;
    int wm = w >> 1, wn = w & 1;
    int bi = blockIdx.y * 128, bj = blockIdx.x * 128;

    floatx4 acc[4][4];
    #pragma unroll
    for (int tm = 0; tm < 4; ++tm)
        #pragma unroll
        for (int tn = 0; tn < 4; ++tn)
            acc[tm][tn] = (floatx4){0.f, 0.f, 0.f, 0.f};

    for (int k0 = 0; k0 < DIM; k0 += 64) {
        // stage A,B tiles: 128 rows x 64 k bf16, XOR-swizzled chunk cols.
        // chunk c: row m=c>>3, swizzled col s=c&7 holds data col q = s^(m&7).
        #pragma unroll
        for (int it = 0; it < 4; ++it) {
            int c = w * 256 + it * 64 + lane;
            int m = c >> 3, s = c & 7;
            int q = s ^ (m & 7);
            ld_g2l_16(A + ((size_t)(bi + m) << 9) + k0 + q * 8,
                      &sA[(w * 256 + it * 64) * 8]);
        }
        #pragma unroll
        for (int it = 0; it < 4; ++it) {
            int c = w * 256 + it * 64 + lane;
            int m = c >> 3, s = c & 7;
            int q = s ^ (m & 7);
            ld_g2l_16(B + ((size_t)(bj + m) << 9) + k0 + q * 8,
                      &sB[(w * 256 + it * 64) * 8]);
        }
        asm volatile("s_waitcnt vmcnt(0)" ::: "memory");
        __syncthreads();

        #pragma unroll
        for (int kk = 0; kk < 2; ++kk) {
            bf16x8 af[4], bfr[4];
            int ml = lane & 15, q = lane >> 4;
            #pragma unroll
            for (int tm = 0; tm < 4; ++tm) {
                int m = wm * 64 + tm * 16 + ml;
                int s = (kk * 4 + q) ^ (m & 7);
                af[tm] = *(const bf16x8*)&sA[m * 64 + s * 8];
            }
            #pragma unroll
            for (int tn = 0; tn < 4; ++tn) {
                int n = wn * 64 + tn * 16 + ml;
                int s = (kk * 4 + q) ^ (n & 7);
                bfr[tn] = *(const bf16x8*)&sB[n * 64 + s * 8];
            }
            #pragma unroll
            for (int tm = 0; tm < 4; ++tm)
                #pragma unroll
                for (int tn = 0; tn < 4; ++tn)
                    acc[tm][tn] = __builtin_amdgcn_mfma_f32_16x16x32_bf16(
                        af[tm], bfr[tn], acc[tm][tn], 0, 0, 0);
        }
        __syncthreads();
    }

    // epilogue: C/D layout col=lane&15, row=(lane>>4)*4+i
    int ml = lane & 15, qd = lane >> 4;
    #pragma unroll
    for (int tm = 0; tm < 4; ++tm) {
        int rowb = bi + wm * 64 + tm * 16 + qd * 4;
        float4 rnr;
        if (MODE == 1) rnr = *(const float4*)&rnorm[rowb];
        #pragma unroll
        for (int tn = 0; tn < 4; ++tn) {
            int col = bj + wn * 64 + tn * 16 + ml;
            float sc = (MODE == 0) ? rnorm[col] : 0.f;
            #pragma unroll
            for (int i = 0; i < 4; ++i) {
                float v = acc[tm][tn][i] * (MODE == 0 ? sc : ((const float*)&rnr)[i]);
                Cmat[(size_t)(rowb + i) * Ndim + col] = v;
            }
        }
    }
}

// ---------------- K4: per-row topk select + class sums + loss ----------------
__device__ inline unsigned f2ord(float f) {
    unsigned u = __float_as_uint(f);
    return (u & 0x80000000u) ? ~u : (u | 0x80000000u);
}

__global__ __launch_bounds__(256) void k_rowloss(const float* __restrict__ sim,
                                                 const int* __restrict__ target,
                                                 float* __restrict__ accs) {
    __shared__ float    s_val[ALLNUM];
    __shared__ float    s_cls[C_CLS];
    __shared__ unsigned s_hist[4][256];
    __shared__ unsigned s_scan[256];
    __shared__ unsigned sh_pref;
    __shared__ int      sh_k;
    __shared__ float    red[4];

    int b = blockIdx.x, t = threadIdx.x;
    const float* row = sim + (size_t)b * ALLNUM;
    int tgt = target[b];
    int jt0 = tgt * NPROXY;

    for (int i = t; i < ALLNUM; i += 256) s_val[i] = row[i];
    for (int i = t; i < C_CLS; i += 256) s_cls[i] = 0.f;
    if (t == 0) { sh_pref = 0u; sh_k = TOPK; }
    __syncthreads();

    unsigned pmask = 0u;
    int wid = t >> 6;
    for (int shift = 24; shift >= 0; shift -= 8) {
        s_hist[0][t] = 0; s_hist[1][t] = 0; s_hist[2][t] = 0; s_hist[3][t] = 0;
        __syncthreads();
        unsigned prefc = sh_pref;
        int kcur = sh_k;
        for (int i = t; i < ALLNUM; i += 256) {
            float f = s_val[i] + (((unsigned)(i - jt0) < (unsigned)NPROXY) ? 1000.0f : 0.0f);
            unsigned u = f2ord(f);
            if ((u & pmask) == prefc)
                atomicAdd(&s_hist[wid][(u >> shift) & 255], 1u);
        }
        __syncthreads();
        unsigned h = s_hist[0][t] + s_hist[1][t] + s_hist[2][t] + s_hist[3][t];
        s_scan[t] = h;
        __syncthreads();
        for (int off = 1; off < 256; off <<= 1) {
            unsigned v = (t + off < 256) ? s_scan[t + off] : 0u;
            __syncthreads();
            s_scan[t] += v;
            __syncthreads();
        }
        unsigned cumGE = s_scan[t];
        if (cumGE >= (unsigned)kcur && cumGE - h < (unsigned)kcur) {
            sh_pref = prefc | ((unsigned)t << shift);
            sh_k = kcur - (int)(cumGE - h);
        }
        pmask |= (0xFFu << shift);
        __syncthreads();
    }
    unsigned thr = sh_pref;

    for (int i = t; i < ALLNUM; i += 256) {
        float f = s_val[i] + (((unsigned)(i - jt0) < (unsigned)NPROXY) ? 1000.0f : 0.0f);
        if (f2ord(f) >= thr)
            atomicAdd(&s_cls[i >> 3], s_val[i]);
    }
    __syncthreads();

    float m = -1e30f;
    for (int c = t; c < C_CLS; c += 256) {
        float v = s_cls[c];
        if (v != 0.0f) m = fmaxf(m, v);
    }
    m = block_reduce(m, 1, red, t);
    float se = 0.f;
    for (int c = t; c < C_CLS; c += 256) {
        float v = s_cls[c];
        if (v != 0.0f) se += expf(v - m);
    }
    se = block_reduce(se, 0, red, t);
    if (t == 0) {
        float lt = s_cls[tgt];
        float predict_t = expf(lt - m) / (1e-8f * expf(-m) + se);
        float loss = -logf(predict_t + 1e-20f);
        atomicAdd(&accs[0], loss);
    }
}

// ---------------- K5b: reg logsumexp - diag over logits [8192][1024] ---------
__global__ __launch_bounds__(256) void k_regloss(const float* __restrict__ logits,
                                                 float* __restrict__ accs) {
    __shared__ float red[4];
    __shared__ float sdiag;
    int t = threadIdx.x;
    float lsum = 0.f;
    for (int r = 0; r < 16; ++r) {
        int i = blockIdx.x * 16 + r;
        const float* row = logits + (size_t)i * C_CLS;
        float4 v = ((const float4*)row)[t];
        int cstar = i >> 3;
        if (t == (cstar >> 2)) sdiag = ((const float*)&v)[cstar & 3];
        float m = fmaxf(fmaxf(v.x, v.y), fmaxf(v.z, v.w));
        m = block_reduce(m, 1, red, t);
        float se = expf(v.x - m) + expf(v.y - m) + expf(v.z - m) + expf(v.w - m);
        se = block_reduce(se, 0, red, t);
        if (t == 0) lsum += m + logf(se) - sdiag;
        __syncthreads();
    }
    if (t == 0) atomicAdd(&accs[1], lsum);
}

// ---------------- K6: finalize -----------------------------------------------
__global__ void k_final(const float* __restrict__ accs, float* __restrict__ out) {
    float lc = accs[0] / (float)BATCH;
    float rg = accs[1] / (float)ALLNUM;
    out[0] = lc + LAM * rg;
    out[1] = lc;
}

extern "C" void kernel_launch(void* const* d_in, const int* in_sizes, int n_in,
                              void* d_out, int out_size, void* d_ws, size_t ws_size,
                              hipStream_t stream) {
    const float* input  = (const float*)d_in[0];
    const int*   target = (const int*)d_in[1];
    const float* P      = (const float*)d_in[2];

    float* ws      = (float*)d_ws;
    float* rnorm   = ws + WS_RNORM;
    float* S       = ws + WS_S;
    ushort_t* Abf  = (ushort_t*)(ws + WS_ABF);
    ushort_t* Pbf  = (ushort_t*)(ws + WS_PBF);
    ushort_t* Stbf = (ushort_t*)(ws + WS_STBF);
    float* accs    = ws + WS_ACC;
    float* sim     = ws + WS_SIM;
    float* logits  = sim;      // reuse: sim dead after k_rowloss
    float* out     = (float*)d_out;

    hipLaunchKernelGGL(k_colnorm, dim3(ALLNUM / 256), dim3(256), 0, stream, P, rnorm, accs);
    hipLaunchKernelGGL(k_convA, dim3(BATCH * DIM / 4 / 256), dim3(256), 0, stream, input, Abf);
    hipLaunchKernelGGL(k_tconv, dim3(ALLNUM / 32, DIM / 32), dim3(256), 0, stream,
                       P, Pbf, DIM, ALLNUM);
    hipLaunchKernelGGL(k_buildS, dim3(DIM * C_CLS / 256), dim3(256), 0, stream, P, rnorm, S);
    hipLaunchKernelGGL(k_tconv, dim3(C_CLS / 32, DIM / 32), dim3(256), 0, stream,
                       S, Stbf, DIM, C_CLS);
    hipLaunchKernelGGL((k_gemm_bt<0>), dim3(ALLNUM / 128, BATCH / 128), dim3(256), 0, stream,
                       Abf, Pbf, rnorm, sim, ALLNUM);
    hipLaunchKernelGGL(k_rowloss, dim3(BATCH), dim3(256), 0, stream, sim, target, accs);
    hipLaunchKernelGGL((k_gemm_bt<1>), dim3(C_CLS / 128, ALLNUM / 128), dim3(256), 0, stream,
                       Pbf, Stbf, rnorm, logits, C_CLS);
    hipLaunchKernelGGL(k_regloss, dim3(ALLNUM / 16), dim3(256), 0, stream, logits, accs);
    hipLaunchKernelGGL(k_final, dim3(1), dim3(1), 0, stream, accs, out);
}

// Round 4
// 234.296 us; speedup vs baseline: 2.4844x; 1.1776x over previous
//
#include <hip/hip_runtime.h>
#include <hip/hip_bf16.h>
#include <math.h>

#define C_CLS   1024
#define NPROXY  8
#define ALLNUM  8192
#define DIM     512
#define TOPK    410
#define LAM     0.3f
#define BATCH   2048

typedef __bf16 bf16x8 __attribute__((ext_vector_type(8)));
typedef float floatx4 __attribute__((ext_vector_type(4)));
typedef unsigned short ushort_t;

// ws layout (float offsets)
#define WS_RNORM 0                      // 8192
#define WS_S     8192                   // 512*1024 fp32 = 524288
#define WS_ABF   532480                 // 2048*512 bf16 = 524288 float-slots
#define WS_PBF   1056768                // 8192*512 bf16 = 2097152 float-slots
#define WS_STBF  3153920                // 1024*512 bf16 = 262144 float-slots
#define WS_ACC   3416064                // 2
#define WS_SIM   3416080                // 2048*8192 fp32 (logits [8192][1024] aliases this)

// ---------------- helpers ----------------------------------------------------
__device__ inline float block_reduce(float v, int is_max, float* red, int t) {
    #pragma unroll
    for (int o = 32; o > 0; o >>= 1) {
        float w = __shfl_down(v, o);
        v = is_max ? fmaxf(v, w) : (v + w);
    }
    __syncthreads();
    if ((t & 63) == 0) red[t >> 6] = v;
    __syncthreads();
    return is_max ? fmaxf(fmaxf(red[0], red[1]), fmaxf(red[2], red[3]))
                  : (red[0] + red[1] + red[2] + red[3]);
}

__device__ inline ushort_t f2bf(float f) {   // RNE float->bf16
    unsigned u = __float_as_uint(f);
    return (ushort_t)((u + 0x7FFFu + ((u >> 16) & 1u)) >> 16);
}

__device__ inline void ld_g2l_16(const void* g, void* l) {
    __builtin_amdgcn_global_load_lds(
        (const __attribute__((address_space(1))) unsigned int*)g,
        (__attribute__((address_space(3))) unsigned int*)l,
        16, 0, 0);
}

__device__ inline unsigned f2ord(float f) {  // monotone float->uint
    unsigned u = __float_as_uint(f);
    return (u & 0x80000000u) ? ~u : (u | 0x80000000u);
}

// ---------------- K1: column 1/norms + zero accumulators ---------------------
__global__ __launch_bounds__(256) void k_colnorm(const float* __restrict__ P,
                                                 float* __restrict__ rnorm,
                                                 float* __restrict__ accs) {
    int j = blockIdx.x * 256 + threadIdx.x;
    float s = 0.f;
    #pragma unroll 8
    for (int d = 0; d < DIM; ++d) {
        float v = P[(size_t)d * ALLNUM + j];
        s += v * v;
    }
    rnorm[j] = 1.0f / fmaxf(sqrtf(s), 1e-12f);
    if (j < 2) accs[j] = 0.f;
}

// ---------------- K2: S[d][c] = sum_{n<8} P[d][8c+n] * rnorm[8c+n] -----------
__global__ __launch_bounds__(256) void k_buildS(const float* __restrict__ P,
                                                const float* __restrict__ rnorm,
                                                float* __restrict__ S) {
    int idx = blockIdx.x * 256 + threadIdx.x;
    int d = idx >> 10;
    int c = idx & (C_CLS - 1);
    const float* p = P + (size_t)d * ALLNUM + c * NPROXY;
    const float* rn = rnorm + c * NPROXY;
    float4 a = *(const float4*)p;
    float4 b = *(const float4*)(p + 4);
    float4 ra = *(const float4*)rn;
    float4 rb = *(const float4*)(rn + 4);
    S[idx] = a.x * ra.x + a.y * ra.y + a.z * ra.z + a.w * ra.w +
             b.x * rb.x + b.y * rb.y + b.z * rb.z + b.w * rb.w;
}

// ---------------- conv: fp32 -> bf16, same layout ----------------------------
__global__ __launch_bounds__(256) void k_convA(const float* __restrict__ src,
                                               ushort_t* __restrict__ dst) {
    int idx = blockIdx.x * 256 + threadIdx.x;          // per float4
    float4 v = ((const float4*)src)[idx];
    ushort4 o;
    o.x = f2bf(v.x); o.y = f2bf(v.y); o.z = f2bf(v.z); o.w = f2bf(v.w);
    ((ushort4*)dst)[idx] = o;
}

// ---------------- conv: fp32 [R][Cc] -> bf16 [Cc][R] (transpose) -------------
__global__ __launch_bounds__(256) void k_tconv(const float* __restrict__ src,
                                               ushort_t* __restrict__ dst,
                                               int R, int Cc) {
    __shared__ float tile[32][33];
    int c0 = blockIdx.x * 32, r0 = blockIdx.y * 32;
    int tc = threadIdx.x & 31, tr = threadIdx.x >> 5;   // tr 0..7
    #pragma unroll
    for (int p = 0; p < 4; ++p)
        tile[tr + p * 8][tc] = src[(size_t)(r0 + tr + p * 8) * Cc + c0 + tc];
    __syncthreads();
    #pragma unroll
    for (int p = 0; p < 4; ++p) {
        int oc = tr + p * 8;
        dst[(size_t)(c0 + oc) * R + r0 + tc] = f2bf(tile[tc][oc]);
    }
}

// ---------------- MFMA GEMM: C[M][N] = A[M][512] * B[N][512]^T ---------------
// MODE 0: C *= rnorm[col] (sim) ; MODE 1: C *= rnorm[row] (reg logits)
template<int MODE>
__global__ __launch_bounds__(256) void k_gemm_bt(const ushort_t* __restrict__ A,
                                                 const ushort_t* __restrict__ B,
                                                 const float* __restrict__ rnorm,
                                                 float* __restrict__ Cmat, int Ndim) {
    __shared__ __align__(16) ushort_t sA[128 * 64];
    __shared__ __align__(16) ushort_t sB[128 * 64];
    int t = threadIdx.x;
    int w = t >> 6, lane = t & 63;
    int wm = w >> 1, wn = w & 1;
    int bi = blockIdx.y * 128, bj = blockIdx.x * 128;

    floatx4 acc[4][4];
    #pragma unroll
    for (int tm = 0; tm < 4; ++tm)
        #pragma unroll
        for (int tn = 0; tn < 4; ++tn)
            acc[tm][tn] = (floatx4){0.f, 0.f, 0.f, 0.f};

    for (int k0 = 0; k0 < DIM; k0 += 64) {
        #pragma unroll
        for (int it = 0; it < 4; ++it) {
            int c = w * 256 + it * 64 + lane;
            int m = c >> 3, s = c & 7;
            int q = s ^ (m & 7);
            ld_g2l_16(A + ((size_t)(bi + m) << 9) + k0 + q * 8,
                      &sA[(w * 256 + it * 64) * 8]);
        }
        #pragma unroll
        for (int it = 0; it < 4; ++it) {
            int c = w * 256 + it * 64 + lane;
            int m = c >> 3, s = c & 7;
            int q = s ^ (m & 7);
            ld_g2l_16(B + ((size_t)(bj + m) << 9) + k0 + q * 8,
                      &sB[(w * 256 + it * 64) * 8]);
        }
        asm volatile("s_waitcnt vmcnt(0)" ::: "memory");
        __syncthreads();

        #pragma unroll
        for (int kk = 0; kk < 2; ++kk) {
            bf16x8 af[4], bfr[4];
            int ml = lane & 15, q = lane >> 4;
            #pragma unroll
            for (int tm = 0; tm < 4; ++tm) {
                int m = wm * 64 + tm * 16 + ml;
                int s = (kk * 4 + q) ^ (m & 7);
                af[tm] = *(const bf16x8*)&sA[m * 64 + s * 8];
            }
            #pragma unroll
            for (int tn = 0; tn < 4; ++tn) {
                int n = wn * 64 + tn * 16 + ml;
                int s = (kk * 4 + q) ^ (n & 7);
                bfr[tn] = *(const bf16x8*)&sB[n * 64 + s * 8];
            }
            #pragma unroll
            for (int tm = 0; tm < 4; ++tm)
                #pragma unroll
                for (int tn = 0; tn < 4; ++tn)
                    acc[tm][tn] = __builtin_amdgcn_mfma_f32_16x16x32_bf16(
                        af[tm], bfr[tn], acc[tm][tn], 0, 0, 0);
        }
        __syncthreads();
    }

    int ml = lane & 15, qd = lane >> 4;
    #pragma unroll
    for (int tm = 0; tm < 4; ++tm) {
        int rowb = bi + wm * 64 + tm * 16 + qd * 4;
        float4 rnr;
        if (MODE == 1) rnr = *(const float4*)&rnorm[rowb];
        #pragma unroll
        for (int tn = 0; tn < 4; ++tn) {
            int col = bj + wn * 64 + tn * 16 + ml;
            float sc = (MODE == 0) ? rnorm[col] : 0.f;
            #pragma unroll
            for (int i = 0; i < 4; ++i) {
                float v = acc[tm][tn][i] * (MODE == 0 ? sc : ((const float*)&rnr)[i]);
                Cmat[(size_t)(rowb + i) * Ndim + col] = v;
            }
        }
    }
}

// ---------------- K4: per-row topk select + class sums + loss ----------------
// Exact 3-level radix select (11+11+10 bits, 2048 bins) with candidate-list
// compaction. Row is re-read from global (L1/L2-hot) instead of LDS-cached:
// LDS ~12.6 KB -> 8 blocks/CU.
#define SEL_BINS 2048
#define SEL_CAP  1024

__global__ __launch_bounds__(256) void k_rowloss(const float* __restrict__ sim,
                                                 const int* __restrict__ target,
                                                 float* __restrict__ accs) {
    __shared__ unsigned s_hist[SEL_BINS];        // 8 KB; later aliased as s_cls
    __shared__ ushort_t s_list[2][SEL_CAP];      // 4 KB candidate lists
    __shared__ unsigned s_wtot[4];
    __shared__ unsigned sh_bin, sh_k, sh_cnt;
    __shared__ float    red[4];

    int b = blockIdx.x, t = threadIdx.x;
    int lane = t & 63, wid = t >> 6;
    const float* row = sim + (size_t)b * ALLNUM;
    int tgt = target[b];

    if (t == 0) { sh_k = TOPK; sh_cnt = 0; }

    unsigned pref = 0;
    unsigned pmask = 0;
    int use_list = 0, cur = 0, cnt = 0, done = 0;
    unsigned thr = 0;

    for (int L = 0; L < 3; ++L) {
        if (done) break;
        int sh = (L == 0) ? 21 : (L == 1) ? 10 : 0;
        // zero histogram
        #pragma unroll
        for (int i = 0; i < SEL_BINS / 256; ++i) s_hist[t + 256 * i] = 0;
        __syncthreads();

        // histogram
        if (L == 0) {
            #pragma unroll 2
            for (int p = 0; p < 8; ++p) {
                int f = t + p * 256;
                float4 v = ((const float4*)row)[f];
                float bo = ((f >> 1) == tgt) ? 1000.0f : 0.0f;
                atomicAdd(&s_hist[(f2ord(v.x + bo) >> 21) & 2047u], 1u);
                atomicAdd(&s_hist[(f2ord(v.y + bo) >> 21) & 2047u], 1u);
                atomicAdd(&s_hist[(f2ord(v.z + bo) >> 21) & 2047u], 1u);
                atomicAdd(&s_hist[(f2ord(v.w + bo) >> 21) & 2047u], 1u);
            }
        } else if (use_list) {
            for (int i = t; i < cnt; i += 256) {
                int col = s_list[cur][i];
                float v = row[col] + (((col >> 3) == tgt) ? 1000.0f : 0.0f);
                atomicAdd(&s_hist[(f2ord(v) >> sh) & 2047u], 1u);
            }
        } else {
            for (int p = 0; p < 8; ++p) {
                int f = t + p * 256;
                float4 v = ((const float4*)row)[f];
                float bo = ((f >> 1) == tgt) ? 1000.0f : 0.0f;
                const float* pv = (const float*)&v;
                #pragma unroll
                for (int e = 0; e < 4; ++e) {
                    unsigned u = f2ord(pv[e] + bo);
                    if ((u & pmask) == pref)
                        atomicAdd(&s_hist[(u >> sh) & 2047u], 1u);
                }
            }
        }
        __syncthreads();

        unsigned kk = sh_k;
        // suffix scan: thread t owns bins [8t, 8t+8)
        unsigned h[8], tsum = 0;
        #pragma unroll
        for (int i = 0; i < 8; ++i) { h[i] = s_hist[8 * t + i]; tsum += h[i]; }
        unsigned v = tsum;
        #pragma unroll
        for (int off = 1; off < 64; off <<= 1) {
            unsigned o = __shfl_down(v, off);
            if (lane + off < 64) v += o;
        }
        if (lane == 0) s_wtot[wid] = v;
        __syncthreads();
        unsigned above = v - tsum;                 // lanes > mine in my wave
        for (int w2 = wid + 1; w2 < 4; ++w2) above += s_wtot[w2];
        // find crossing bin among my 8
        unsigned sfx = 0;
        int found = -1; unsigned knew = 0;
        #pragma unroll
        for (int i = 7; i >= 0; --i) {
            sfx += h[i];
            unsigned cum = above + sfx;
            if (cum >= kk && cum - h[i] < kk) { found = i; knew = kk - (cum - h[i]); }
        }
        __syncthreads();                           // protect sh_k/sh_cnt reuse
        if (found >= 0) { sh_bin = 8 * t + (unsigned)found; sh_k = knew; }
        if (t == 0) sh_cnt = 0;
        __syncthreads();

        unsigned B = sh_bin;
        unsigned kq = sh_k;
        pref |= B << sh;
        pmask = (L == 0) ? 0xFFE00000u : (L == 1) ? 0xFFFFFC00u : 0xFFFFFFFFu;

        if (L == 2) { thr = pref; break; }

        // compact candidates matching new prefix
        int nxt = cur ^ 1;
        if (L == 0 || !use_list) {
            for (int p = 0; p < 8; ++p) {
                int f = t + p * 256;
                float4 vv = ((const float4*)row)[f];
                float bo = ((f >> 1) == tgt) ? 1000.0f : 0.0f;
                const float* pv = (const float*)&vv;
                #pragma unroll
                for (int e = 0; e < 4; ++e) {
                    unsigned u = f2ord(pv[e] + bo);
                    if ((u & pmask) == pref) {
                        unsigned idx = atomicAdd(&sh_cnt, 1u);
                        if (idx < SEL_CAP) s_list[nxt][idx] = (ushort_t)(4 * f + e);
                    }
                }
            }
        } else {
            for (int i = t; i < cnt; i += 256) {
                int col = s_list[cur][i];
                unsigned u = f2ord(row[col] + (((col >> 3) == tgt) ? 1000.0f : 0.0f));
                if ((u & pmask) == pref) {
                    unsigned idx = atomicAdd(&sh_cnt, 1u);
                    if (idx < SEL_CAP) s_list[nxt][idx] = (ushort_t)col;
                }
            }
        }
        __syncthreads();
        unsigned c2 = sh_cnt;
        if (c2 == kq) { thr = pref; done = 1; }   // all bin members included
        use_list = (c2 <= SEL_CAP);
        cur = nxt; cnt = (int)c2;
    }

    // class sums (alias s_hist as float bins)
    float* s_cls = (float*)s_hist;
    __syncthreads();
    #pragma unroll
    for (int i = 0; i < 4; ++i) s_cls[t + 256 * i] = 0.f;
    __syncthreads();
    for (int p = 0; p < 8; ++p) {
        int f = t + p * 256;
        float4 vv = ((const float4*)row)[f];
        float bo = ((f >> 1) == tgt) ? 1000.0f : 0.0f;
        const float* pv = (const float*)&vv;
        #pragma unroll
        for (int e = 0; e < 4; ++e) {
            if (f2ord(pv[e] + bo) >= thr)
                atomicAdd(&s_cls[(4 * f + e) >> 3], pv[e]);
        }
    }
    __syncthreads();

    // masked (logit != 0) stable softmax loss
    float m = -1e30f;
    for (int c = t; c < C_CLS; c += 256) {
        float vv = s_cls[c];
        if (vv != 0.0f) m = fmaxf(m, vv);
    }
    m = block_reduce(m, 1, red, t);
    float se = 0.f;
    for (int c = t; c < C_CLS; c += 256) {
        float vv = s_cls[c];
        if (vv != 0.0f) se += expf(vv - m);
    }
    se = block_reduce(se, 0, red, t);
    if (t == 0) {
        float lt = s_cls[tgt];
        float predict_t = expf(lt - m) / (1e-8f * expf(-m) + se);
        float loss = -logf(predict_t + 1e-20f);
        atomicAdd(&accs[0], loss);
    }
}

// ---------------- K5b: reg logsumexp - diag, one wave per row ----------------
__global__ __launch_bounds__(256) void k_regloss(const float* __restrict__ logits,
                                                 float* __restrict__ accs) {
    __shared__ float bsum[4];
    int t = threadIdx.x, lane = t & 63, wid = t >> 6;
    int i = blockIdx.x * 4 + wid;
    const float* row = logits + (size_t)i * C_CLS;
    float4 v[4];
    #pragma unroll
    for (int c = 0; c < 4; ++c) v[c] = ((const float4*)row)[lane + 64 * c];

    int cstar = i >> 3;
    float sd = 0.f;
    { int q = cstar >> 2;
      if (lane == (q & 63)) sd = ((const float*)&v[q >> 6])[cstar & 3]; }

    float m = -1e30f;
    #pragma unroll
    for (int c = 0; c < 4; ++c)
        m = fmaxf(m, fmaxf(fmaxf(v[c].x, v[c].y), fmaxf(v[c].z, v[c].w)));
    #pragma unroll
    for (int off = 32; off > 0; off >>= 1) m = fmaxf(m, __shfl_xor(m, off));

    float se = 0.f;
    #pragma unroll
    for (int c = 0; c < 4; ++c)
        se += expf(v[c].x - m) + expf(v[c].y - m) + expf(v[c].z - m) + expf(v[c].w - m);
    #pragma unroll
    for (int off = 32; off > 0; off >>= 1) se += __shfl_xor(se, off);
    #pragma unroll
    for (int off = 32; off > 0; off >>= 1) sd += __shfl_xor(sd, off);

    if (lane == 0) bsum[wid] = m + logf(se) - sd;
    __syncthreads();
    if (t == 0)
        atomicAdd(&accs[1], bsum[0] + bsum[1] + bsum[2] + bsum[3]);
}

// ---------------- K6: finalize -----------------------------------------------
__global__ void k_final(const float* __restrict__ accs, float* __restrict__ out) {
    float lc = accs[0] / (float)BATCH;
    float rg = accs[1] / (float)ALLNUM;
    out[0] = lc + LAM * rg;
    out[1] = lc;
}

extern "C" void kernel_launch(void* const* d_in, const int* in_sizes, int n_in,
                              void* d_out, int out_size, void* d_ws, size_t ws_size,
                              hipStream_t stream) {
    const float* input  = (const float*)d_in[0];
    const int*   target = (const int*)d_in[1];
    const float* P      = (const float*)d_in[2];

    float* ws      = (float*)d_ws;
    float* rnorm   = ws + WS_RNORM;
    float* S       = ws + WS_S;
    ushort_t* Abf  = (ushort_t*)(ws + WS_ABF);
    ushort_t* Pbf  = (ushort_t*)(ws + WS_PBF);
    ushort_t* Stbf = (ushort_t*)(ws + WS_STBF);
    float* accs    = ws + WS_ACC;
    float* sim     = ws + WS_SIM;
    float* logits  = sim;      // reuse: sim dead after k_rowloss
    float* out     = (float*)d_out;

    hipLaunchKernelGGL(k_colnorm, dim3(ALLNUM / 256), dim3(256), 0, stream, P, rnorm, accs);
    hipLaunchKernelGGL(k_convA, dim3(BATCH * DIM / 4 / 256), dim3(256), 0, stream, input, Abf);
    hipLaunchKernelGGL(k_tconv, dim3(ALLNUM / 32, DIM / 32), dim3(256), 0, stream,
                       P, Pbf, DIM, ALLNUM);
    hipLaunchKernelGGL(k_buildS, dim3(DIM * C_CLS / 256), dim3(256), 0, stream, P, rnorm, S);
    hipLaunchKernelGGL(k_tconv, dim3(C_CLS / 32, DIM / 32), dim3(256), 0, stream,
                       S, Stbf, DIM, C_CLS);
    hipLaunchKernelGGL((k_gemm_bt<0>), dim3(ALLNUM / 128, BATCH / 128), dim3(256), 0, stream,
                       Abf, Pbf, rnorm, sim, ALLNUM);
    hipLaunchKernelGGL(k_rowloss, dim3(BATCH), dim3(256), 0, stream, sim, target, accs);
    hipLaunchKernelGGL((k_gemm_bt<1>), dim3(C_CLS / 128, ALLNUM / 128), dim3(256), 0, stream,
                       Pbf, Stbf, rnorm, logits, C_CLS);
    hipLaunchKernelGGL(k_regloss, dim3(ALLNUM / 4), dim3(256), 0, stream, logits, accs);
    hipLaunchKernelGGL(k_final, dim3(1), dim3(1), 0, stream, accs, out);
}

// Round 5
// 226.543 us; speedup vs baseline: 2.5694x; 1.0342x over previous
//
#include <hip/hip_runtime.h>
#include <hip/hip_bf16.h>
#include <math.h>

#define C_CLS   1024
#define NPROXY  8
#define ALLNUM  8192
#define DIM     512
#define TOPK    410
#define LAM     0.3f
#define BATCH   2048

typedef __bf16 bf16x8 __attribute__((ext_vector_type(8)));
typedef float floatx4 __attribute__((ext_vector_type(4)));
typedef unsigned short ushort_t;

// ws layout (float offsets)
#define WS_RNORM 0                      // 8192
#define WS_ABF   8192                   // 2048*512 bf16 = 524288 float-slots
#define WS_PBF   532480                 // 8192*512 bf16 = 2097152 float-slots
#define WS_STBF  2629632                // 1024*512 bf16 = 262144 float-slots
#define WS_ACC   2891776                // 16 (padded)
#define WS_SIM   2891792                // 2048*8192 fp32; logits bf16 alias after rowloss

// ---------------- helpers ----------------------------------------------------
__device__ inline float block_reduce(float v, int is_max, float* red, int t) {
    #pragma unroll
    for (int o = 32; o > 0; o >>= 1) {
        float w = __shfl_down(v, o);
        v = is_max ? fmaxf(v, w) : (v + w);
    }
    __syncthreads();
    if ((t & 63) == 0) red[t >> 6] = v;
    __syncthreads();
    return is_max ? fmaxf(fmaxf(red[0], red[1]), fmaxf(red[2], red[3]))
                  : (red[0] + red[1] + red[2] + red[3]);
}

__device__ inline ushort_t f2bf(float f) {   // RNE float->bf16
    unsigned u = __float_as_uint(f);
    return (ushort_t)((u + 0x7FFFu + ((u >> 16) & 1u)) >> 16);
}

__device__ inline void ld_g2l_16(const void* g, void* l) {
    __builtin_amdgcn_global_load_lds(
        (const __attribute__((address_space(1))) unsigned int*)g,
        (__attribute__((address_space(3))) unsigned int*)l,
        16, 0, 0);
}

__device__ inline unsigned f2ord(float f) {  // monotone float->uint
    unsigned u = __float_as_uint(f);
    return (u & 0x80000000u) ? ~u : (u | 0x80000000u);
}

// ---------------- K1: fused prep (colnorm | convA | tconv P) -----------------
__global__ __launch_bounds__(256) void k_prep1(const float* __restrict__ P,
                                               const float* __restrict__ input,
                                               float* __restrict__ rnorm,
                                               ushort_t* __restrict__ Abf,
                                               ushort_t* __restrict__ Pbf,
                                               float* __restrict__ accs) {
    __shared__ float tile[32][33];
    int bx = blockIdx.x, t = threadIdx.x;
    if (bx < 32) {
        // colnorm: 1/||P[:,j]|| + zero accs
        int j = bx * 256 + t;
        float s = 0.f;
        #pragma unroll 8
        for (int d = 0; d < DIM; ++d) {
            float v = P[(size_t)d * ALLNUM + j];
            s += v * v;
        }
        rnorm[j] = 1.0f / fmaxf(sqrtf(s), 1e-12f);
        if (j < 2) accs[j] = 0.f;
    } else if (bx < 32 + 1024) {
        // convA: input fp32 -> bf16 same layout
        int idx = (bx - 32) * 256 + t;
        float4 v = ((const float4*)input)[idx];
        ushort4 o;
        o.x = f2bf(v.x); o.y = f2bf(v.y); o.z = f2bf(v.z); o.w = f2bf(v.w);
        ((ushort4*)Abf)[idx] = o;
    } else {
        // tconv: P [512][8192] fp32 -> Pbf [8192][512] bf16
        int id = bx - 1056;
        int c0 = (id & 255) * 32, r0 = (id >> 8) * 32;
        int tc = t & 31, tr = t >> 5;
        #pragma unroll
        for (int p = 0; p < 4; ++p)
            tile[tr + p * 8][tc] = P[(size_t)(r0 + tr + p * 8) * ALLNUM + c0 + tc];
        __syncthreads();
        #pragma unroll
        for (int p = 0; p < 4; ++p) {
            int oc = tr + p * 8;
            Pbf[(size_t)(c0 + oc) * DIM + r0 + tc] = f2bf(tile[tc][oc]);
        }
    }
}

// ---------------- K2: S^T bf16 direct: St[c][d] = sum_n P[d][8c+n]*rn[8c+n] --
__global__ __launch_bounds__(256) void k_prep2(const float* __restrict__ P,
                                               const float* __restrict__ rnorm,
                                               ushort_t* __restrict__ Stbf) {
    __shared__ float tile[32][33];       // [d_local][c_local]
    int bx = blockIdx.x, t = threadIdx.x;
    int c0 = (bx & 31) * 32, d0 = (bx >> 5) * 32;
    int cl = t & 31, dl8 = t >> 5;       // dl8 in 0..7
    #pragma unroll
    for (int p = 0; p < 4; ++p) {
        int d = d0 + dl8 + 8 * p;
        int c = c0 + cl;
        const float* pp = P + (size_t)d * ALLNUM + c * NPROXY;
        const float* rn = rnorm + c * NPROXY;
        float4 a = *(const float4*)pp;
        float4 b = *(const float4*)(pp + 4);
        float4 ra = *(const float4*)rn;
        float4 rb = *(const float4*)(rn + 4);
        tile[dl8 + 8 * p][cl] = a.x * ra.x + a.y * ra.y + a.z * ra.z + a.w * ra.w +
                                b.x * rb.x + b.y * rb.y + b.z * rb.z + b.w * rb.w;
    }
    __syncthreads();
    #pragma unroll
    for (int p = 0; p < 4; ++p) {
        int cl2 = dl8 + 8 * p, dl2 = t & 31;
        Stbf[(size_t)(c0 + cl2) * DIM + d0 + dl2] = f2bf(tile[dl2][cl2]);
    }
}

// ---------------- MFMA GEMM: C[M][N] = A[M][512] * B[N][512]^T ---------------
// MODE 0: C(f32) *= rnorm[col] (sim) ; MODE 1: C(bf16) *= rnorm[row] (logits)
template<int MODE>
__global__ __launch_bounds__(256) void k_gemm_bt(const ushort_t* __restrict__ A,
                                                 const ushort_t* __restrict__ B,
                                                 const float* __restrict__ rnorm,
                                                 void* __restrict__ Cmat, int Ndim) {
    __shared__ __align__(16) ushort_t sA[128 * 64];
    __shared__ __align__(16) ushort_t sB[128 * 64];
    int t = threadIdx.x;
    int w = t >> 6, lane = t & 63;
    int wm = w >> 1, wn = w & 1;
    int bi = blockIdx.y * 128, bj = blockIdx.x * 128;

    floatx4 acc[4][4];
    #pragma unroll
    for (int tm = 0; tm < 4; ++tm)
        #pragma unroll
        for (int tn = 0; tn < 4; ++tn)
            acc[tm][tn] = (floatx4){0.f, 0.f, 0.f, 0.f};

    for (int k0 = 0; k0 < DIM; k0 += 64) {
        #pragma unroll
        for (int it = 0; it < 4; ++it) {
            int c = w * 256 + it * 64 + lane;
            int m = c >> 3, s = c & 7;
            int q = s ^ (m & 7);
            ld_g2l_16(A + ((size_t)(bi + m) << 9) + k0 + q * 8,
                      &sA[(w * 256 + it * 64) * 8]);
        }
        #pragma unroll
        for (int it = 0; it < 4; ++it) {
            int c = w * 256 + it * 64 + lane;
            int m = c >> 3, s = c & 7;
            int q = s ^ (m & 7);
            ld_g2l_16(B + ((size_t)(bj + m) << 9) + k0 + q * 8,
                      &sB[(w * 256 + it * 64) * 8]);
        }
        asm volatile("s_waitcnt vmcnt(0)" ::: "memory");
        __syncthreads();

        #pragma unroll
        for (int kk = 0; kk < 2; ++kk) {
            bf16x8 af[4], bfr[4];
            int ml = lane & 15, q = lane >> 4;
            #pragma unroll
            for (int tm = 0; tm < 4; ++tm) {
                int m = wm * 64 + tm * 16 + ml;
                int s = (kk * 4 + q) ^ (m & 7);
                af[tm] = *(const bf16x8*)&sA[m * 64 + s * 8];
            }
            #pragma unroll
            for (int tn = 0; tn < 4; ++tn) {
                int n = wn * 64 + tn * 16 + ml;
                int s = (kk * 4 + q) ^ (n & 7);
                bfr[tn] = *(const bf16x8*)&sB[n * 64 + s * 8];
            }
            #pragma unroll
            for (int tm = 0; tm < 4; ++tm)
                #pragma unroll
                for (int tn = 0; tn < 4; ++tn)
                    acc[tm][tn] = __builtin_amdgcn_mfma_f32_16x16x32_bf16(
                        af[tm], bfr[tn], acc[tm][tn], 0, 0, 0);
        }
        __syncthreads();
    }

    int ml = lane & 15, qd = lane >> 4;
    #pragma unroll
    for (int tm = 0; tm < 4; ++tm) {
        int rowb = bi + wm * 64 + tm * 16 + qd * 4;
        float4 rnr;
        if (MODE == 1) rnr = *(const float4*)&rnorm[rowb];
        #pragma unroll
        for (int tn = 0; tn < 4; ++tn) {
            int col = bj + wn * 64 + tn * 16 + ml;
            float sc = (MODE == 0) ? rnorm[col] : 0.f;
            #pragma unroll
            for (int i = 0; i < 4; ++i) {
                float v = acc[tm][tn][i] * (MODE == 0 ? sc : ((const float*)&rnr)[i]);
                size_t idx = (size_t)(rowb + i) * Ndim + col;
                if (MODE == 0) ((float*)Cmat)[idx] = v;
                else           ((ushort_t*)Cmat)[idx] = f2bf(v);
            }
        }
    }
}

// ---------------- K4: per-row topk select + class sums + loss ----------------
// Level-0 radix (11-bit, 2048 bins) -> compact crossing-bin candidates ->
// direct rank-selection on the candidate list (typ. ~100 entries). Full radix
// fallback only if candidates overflow SEL_CAP.
#define SEL_BINS 2048
#define SEL_CAP  1024

__device__ inline void suffix_select(unsigned* s_hist, int nb, unsigned kk,
                                     unsigned* s_wtot, unsigned* sh_bin,
                                     unsigned* sh_k, int t, int lane, int wid) {
    int per = nb >> 8;                          // bins per thread (8 or 4)
    unsigned h[8], tsum = 0;
    for (int i = 0; i < per; ++i) { h[i] = s_hist[per * t + i]; tsum += h[i]; }
    unsigned v = tsum;
    #pragma unroll
    for (int off = 1; off < 64; off <<= 1) {
        unsigned o = __shfl_down(v, off);
        if (lane + off < 64) v += o;
    }
    if (lane == 0) s_wtot[wid] = v;
    __syncthreads();
    unsigned above = v - tsum;
    for (int w2 = wid + 1; w2 < 4; ++w2) above += s_wtot[w2];
    unsigned sfx = 0; int found = -1; unsigned knew = 0;
    for (int i = per - 1; i >= 0; --i) {
        sfx += h[i];
        unsigned cum = above + sfx;
        if (cum >= kk && cum - h[i] < kk) { found = i; knew = kk - (cum - h[i]); }
    }
    if (found >= 0) { *sh_bin = per * t + (unsigned)found; *sh_k = knew; }
    __syncthreads();
}

__global__ __launch_bounds__(256) void k_rowloss(const float* __restrict__ sim,
                                                 const int* __restrict__ target,
                                                 float* __restrict__ accs) {
    __shared__ unsigned s_hist[SEL_BINS];        // 8 KB; aliased as s_cls later
    __shared__ unsigned s_ord[SEL_CAP];          // 4 KB candidate ord values
    __shared__ unsigned s_wtot[4];
    __shared__ unsigned sh_bin, sh_k, sh_cnt, sh_thr;
    __shared__ float    red[4];

    int b = blockIdx.x, t = threadIdx.x;
    int lane = t & 63, wid = t >> 6;
    const float* row = sim + (size_t)b * ALLNUM;
    int tgt = target[b];

    if (t == 0) sh_cnt = 0;
    // ---- level 0 histogram (top 11 bits) ----
    #pragma unroll
    for (int i = 0; i < SEL_BINS / 256; ++i) s_hist[t + 256 * i] = 0;
    __syncthreads();
    for (int p = 0; p < 8; ++p) {
        int f = t + p * 256;
        float4 v = ((const float4*)row)[f];
        float bo = ((f >> 1) == tgt) ? 1000.0f : 0.0f;
        atomicAdd(&s_hist[f2ord(v.x + bo) >> 21], 1u);
        atomicAdd(&s_hist[f2ord(v.y + bo) >> 21], 1u);
        atomicAdd(&s_hist[f2ord(v.z + bo) >> 21], 1u);
        atomicAdd(&s_hist[f2ord(v.w + bo) >> 21], 1u);
    }
    __syncthreads();
    suffix_select(s_hist, SEL_BINS, TOPK, s_wtot, &sh_bin, &sh_k, t, lane, wid);
    unsigned B0 = sh_bin;
    unsigned kq = sh_k;

    // ---- compact crossing-bin candidates ----
    for (int p = 0; p < 8; ++p) {
        int f = t + p * 256;
        float4 v = ((const float4*)row)[f];
        float bo = ((f >> 1) == tgt) ? 1000.0f : 0.0f;
        const float* pv = (const float*)&v;
        #pragma unroll
        for (int e = 0; e < 4; ++e) {
            unsigned u = f2ord(pv[e] + bo);
            if ((u >> 21) == B0) {
                unsigned idx = atomicAdd(&sh_cnt, 1u);
                if (idx < SEL_CAP) s_ord[idx] = u;
            }
        }
    }
    __syncthreads();
    int cnt = (int)sh_cnt;
    unsigned thr;

    if (cnt <= SEL_CAP) {
        // ---- direct rank-selection: kq-th largest of cnt candidates ----
        for (int j = t; j < cnt; j += 256) {
            unsigned mine = s_ord[j];
            unsigned g = 0, geq = 0;
            for (int i = 0; i < cnt; ++i) {
                unsigned o = s_ord[i];
                g   += (o > mine) ? 1u : 0u;
                geq += (o >= mine) ? 1u : 0u;
            }
            if (g < kq && geq >= kq) sh_thr = mine;   // all writers agree (ties)
        }
        __syncthreads();
        thr = sh_thr;
    } else {
        // ---- fallback: radix levels on bits [20:10] then [9:0] ----
        #pragma unroll
        for (int i = 0; i < SEL_BINS / 256; ++i) s_hist[t + 256 * i] = 0;
        __syncthreads();
        for (int p = 0; p < 8; ++p) {
            int f = t + p * 256;
            float4 v = ((const float4*)row)[f];
            float bo = ((f >> 1) == tgt) ? 1000.0f : 0.0f;
            const float* pv = (const float*)&v;
            #pragma unroll
            for (int e = 0; e < 4; ++e) {
                unsigned u = f2ord(pv[e] + bo);
                if ((u >> 21) == B0) atomicAdd(&s_hist[(u >> 10) & 2047u], 1u);
            }
        }
        __syncthreads();
        suffix_select(s_hist, 2048, kq, s_wtot, &sh_bin, &sh_k, t, lane, wid);
        unsigned B1 = sh_bin, kq1 = sh_k;
        unsigned pref21 = (B0 << 11) | B1;

        #pragma unroll
        for (int i = 0; i < 4; ++i) s_hist[t + 256 * i] = 0;
        __syncthreads();
        for (int p = 0; p < 8; ++p) {
            int f = t + p * 256;
            float4 v = ((const float4*)row)[f];
            float bo = ((f >> 1) == tgt) ? 1000.0f : 0.0f;
            const float* pv = (const float*)&v;
            #pragma unroll
            for (int e = 0; e < 4; ++e) {
                unsigned u = f2ord(pv[e] + bo);
                if ((u >> 10) == pref21) atomicAdd(&s_hist[u & 1023u], 1u);
            }
        }
        __syncthreads();
        suffix_select(s_hist, 1024, kq1, s_wtot, &sh_bin, &sh_k, t, lane, wid);
        thr = (pref21 << 10) | sh_bin;
    }

    // ---- class sums (alias s_hist as float bins) ----
    float* s_cls = (float*)s_hist;
    __syncthreads();
    #pragma unroll
    for (int i = 0; i < 4; ++i) s_cls[t + 256 * i] = 0.f;
    __syncthreads();
    for (int p = 0; p < 8; ++p) {
        int f = t + p * 256;
        float4 vv = ((const float4*)row)[f];
        float bo = ((f >> 1) == tgt) ? 1000.0f : 0.0f;
        const float* pv = (const float*)&vv;
        #pragma unroll
        for (int e = 0; e < 4; ++e) {
            if (f2ord(pv[e] + bo) >= thr)
                atomicAdd(&s_cls[(4 * f + e) >> 3], pv[e]);
        }
    }
    __syncthreads();

    // ---- masked (logit != 0) stable softmax loss ----
    float m = -1e30f;
    for (int c = t; c < C_CLS; c += 256) {
        float vv = s_cls[c];
        if (vv != 0.0f) m = fmaxf(m, vv);
    }
    m = block_reduce(m, 1, red, t);
    float se = 0.f;
    for (int c = t; c < C_CLS; c += 256) {
        float vv = s_cls[c];
        if (vv != 0.0f) se += expf(vv - m);
    }
    se = block_reduce(se, 0, red, t);
    if (t == 0) {
        float lt = s_cls[tgt];
        float predict_t = expf(lt - m) / (1e-8f * expf(-m) + se);
        float loss = -logf(predict_t + 1e-20f);
        atomicAdd(&accs[0], loss);
    }
}

// ---------------- K5b: reg logsumexp - diag, one wave per row (bf16 in) ------
__global__ __launch_bounds__(256) void k_regloss(const ushort_t* __restrict__ logits,
                                                 float* __restrict__ accs) {
    __shared__ float bsum[4];
    int t = threadIdx.x, lane = t & 63, wid = t >> 6;
    int i = blockIdx.x * 4 + wid;
    const ushort_t* row = logits + (size_t)i * C_CLS;
    uint4 c0 = ((const uint4*)row)[lane];            // elements 8*lane .. +7
    uint4 c1 = ((const uint4*)(row + 512))[lane];    // elements 512+8*lane .. +7

    float f[16];
    const unsigned* u0 = (const unsigned*)&c0;
    const unsigned* u1 = (const unsigned*)&c1;
    #pragma unroll
    for (int k = 0; k < 4; ++k) {
        f[2 * k]     = __uint_as_float(u0[k] << 16);
        f[2 * k + 1] = __uint_as_float(u0[k] & 0xFFFF0000u);
        f[8 + 2 * k]     = __uint_as_float(u1[k] << 16);
        f[8 + 2 * k + 1] = __uint_as_float(u1[k] & 0xFFFF0000u);
    }

    int cstar = i >> 3;                  // diag class
    int chunk = cstar >> 9, within = cstar & 511;
    float sd = 0.f;
    if (lane == (within >> 3)) sd = f[chunk * 8 + (within & 7)];

    float m = -1e30f;
    #pragma unroll
    for (int k = 0; k < 16; ++k) m = fmaxf(m, f[k]);
    #pragma unroll
    for (int off = 32; off > 0; off >>= 1) m = fmaxf(m, __shfl_xor(m, off));

    float se = 0.f;
    #pragma unroll
    for (int k = 0; k < 16; ++k) se += expf(f[k] - m);
    #pragma unroll
    for (int off = 32; off > 0; off >>= 1) se += __shfl_xor(se, off);
    #pragma unroll
    for (int off = 32; off > 0; off >>= 1) sd += __shfl_xor(sd, off);

    if (lane == 0) bsum[wid] = m + logf(se) - sd;
    __syncthreads();
    if (t == 0)
        atomicAdd(&accs[1], bsum[0] + bsum[1] + bsum[2] + bsum[3]);
}

// ---------------- K6: finalize -----------------------------------------------
__global__ void k_final(const float* __restrict__ accs, float* __restrict__ out) {
    float lc = accs[0] / (float)BATCH;
    float rg = accs[1] / (float)ALLNUM;
    out[0] = lc + LAM * rg;
    out[1] = lc;
}

extern "C" void kernel_launch(void* const* d_in, const int* in_sizes, int n_in,
                              void* d_out, int out_size, void* d_ws, size_t ws_size,
                              hipStream_t stream) {
    const float* input  = (const float*)d_in[0];
    const int*   target = (const int*)d_in[1];
    const float* P      = (const float*)d_in[2];

    float* ws      = (float*)d_ws;
    float* rnorm   = ws + WS_RNORM;
    ushort_t* Abf  = (ushort_t*)(ws + WS_ABF);
    ushort_t* Pbf  = (ushort_t*)(ws + WS_PBF);
    ushort_t* Stbf = (ushort_t*)(ws + WS_STBF);
    float* accs    = ws + WS_ACC;
    float* sim     = ws + WS_SIM;
    ushort_t* logits = (ushort_t*)sim;   // reuse: sim dead after k_rowloss
    float* out     = (float*)d_out;

    hipLaunchKernelGGL(k_prep1, dim3(32 + 1024 + 4096), dim3(256), 0, stream,
                       P, input, rnorm, Abf, Pbf, accs);
    hipLaunchKernelGGL(k_prep2, dim3((C_CLS / 32) * (DIM / 32)), dim3(256), 0, stream,
                       P, rnorm, Stbf);
    hipLaunchKernelGGL((k_gemm_bt<0>), dim3(ALLNUM / 128, BATCH / 128), dim3(256), 0, stream,
                       Abf, Pbf, rnorm, sim, ALLNUM);
    hipLaunchKernelGGL(k_rowloss, dim3(BATCH), dim3(256), 0, stream, sim, target, accs);
    hipLaunchKernelGGL((k_gemm_bt<1>), dim3(C_CLS / 128, ALLNUM / 128), dim3(256), 0, stream,
                       Pbf, Stbf, rnorm, logits, C_CLS);
    hipLaunchKernelGGL(k_regloss, dim3(ALLNUM / 4), dim3(256), 0, stream, logits, accs);
    hipLaunchKernelGGL(k_final, dim3(1), dim3(1), 0, stream, accs, out);
}